// Round 1
// baseline (3150.267 us; speedup 1.0000x reference)
//
#include <hip/hip_runtime.h>
#include <hip/hip_bf16.h>
#include <cstddef>

// Problem constants
#define NB 4
#define NL 1024
#define IN_DIM 64
#define D_MODEL 512
#define N_LAYERS 3
#define D_INNER 1024
#define NSTATE 16
#define DT_RANK 32
#define KCONV 4
#define NROWS (NB * NL)   // 4096

// ---------------------------------------------------------------------------
// Generic tiled fp32 GEMM: C[M,N] = A[M,lda(>=K)] @ W[N,K]^T (+bias) (+act)
// act: 0 = none, 1 = softplus
// Requires: M % 64 == 0, N % 64 == 0, K % 16 == 0.
// ---------------------------------------------------------------------------
__global__ __launch_bounds__(256) void gemm_atb(
    const float* __restrict__ A, int lda,
    const float* __restrict__ W,
    const float* __restrict__ bias,
    float* __restrict__ C,
    int M, int N, int K, int act)
{
  __shared__ float sa[16][65];
  __shared__ float sb[16][65];
  const int tid = threadIdx.x;
  const int tx = tid & 15, ty = tid >> 4;
  const int m0 = blockIdx.y * 64, n0 = blockIdx.x * 64;
  const int lrow = tid >> 2;        // 0..63
  const int lk = (tid & 3) << 2;    // 0,4,8,12
  float acc[4][4] = {};

  for (int k0 = 0; k0 < K; k0 += 16) {
    float4 av = *(const float4*)(A + (size_t)(m0 + lrow) * lda + k0 + lk);
    float4 wv = *(const float4*)(W + (size_t)(n0 + lrow) * K + k0 + lk);
    sa[lk + 0][lrow] = av.x; sa[lk + 1][lrow] = av.y;
    sa[lk + 2][lrow] = av.z; sa[lk + 3][lrow] = av.w;
    sb[lk + 0][lrow] = wv.x; sb[lk + 1][lrow] = wv.y;
    sb[lk + 2][lrow] = wv.z; sb[lk + 3][lrow] = wv.w;
    __syncthreads();
#pragma unroll
    for (int kk = 0; kk < 16; ++kk) {
      float a[4], b[4];
#pragma unroll
      for (int i = 0; i < 4; ++i) a[i] = sa[kk][(ty << 2) + i];
#pragma unroll
      for (int j = 0; j < 4; ++j) b[j] = sb[kk][(tx << 2) + j];
#pragma unroll
      for (int i = 0; i < 4; ++i)
#pragma unroll
        for (int j = 0; j < 4; ++j)
          acc[i][j] = fmaf(a[i], b[j], acc[i][j]);
    }
    __syncthreads();
  }

#pragma unroll
  for (int i = 0; i < 4; ++i) {
    const int m = m0 + (ty << 2) + i;
#pragma unroll
    for (int j = 0; j < 4; ++j) {
      const int n = n0 + (tx << 2) + j;
      float v = acc[i][j];
      if (bias) v += bias[n];
      if (act == 1) v = (v > 20.f) ? v : log1pf(__expf(v));
      C[(size_t)m * N + n] = v;
    }
  }
}

// ---------------------------------------------------------------------------
// Depthwise causal conv (K=4) + SiLU.
// xz is (NROWS, 2*D_INNER); xp = first D_INNER columns.
// xc[b,t,d] = silu( sum_j xp[b, t-3+j, d] * cw[d,j] + cb[d] )
// ---------------------------------------------------------------------------
__global__ __launch_bounds__(256) void conv_silu(
    const float* __restrict__ xz,
    const float* __restrict__ cw,
    const float* __restrict__ cb,
    float* __restrict__ xc)
{
  const int idx = blockIdx.x * 256 + threadIdx.x;   // over NB*NL*D_INNER
  const int d = idx & (D_INNER - 1);
  const int bt = idx >> 10;
  const int t = bt & (NL - 1);
  const int b = bt >> 10;

  float accv = cb[d];
#pragma unroll
  for (int j = 0; j < KCONV; ++j) {
    const int tt = t - (KCONV - 1) + j;
    if (tt >= 0)
      accv = fmaf(xz[((size_t)(b * NL + tt)) * (2 * D_INNER) + d], cw[d * KCONV + j], accv);
  }
  const float sig = 1.f / (1.f + __expf(-accv));
  xc[idx] = accv * sig;
}

// ---------------------------------------------------------------------------
// Selective scan. One thread per (b, d): 16 states in registers, loop t.
// Reads dt (softplus'd), xc; proj rows hold [dtl(32) | B(16) | C(16)].
// Writes y (gated) IN PLACE over xc.
// ---------------------------------------------------------------------------
__global__ __launch_bounds__(256) void scan_kernel(
    const float* __restrict__ dt,
    const float* __restrict__ proj,
    const float* __restrict__ xz,     // for z = xz[..., D_INNER:]
    const float* __restrict__ A_log,
    const float* __restrict__ Dp,
    float* xc)                        // in: xc, out: gated y (same buffer)
{
  const int d = blockIdx.x * 256 + threadIdx.x;  // 0..1023
  const int b = blockIdx.y;

  float A2[NSTATE];
#pragma unroll
  for (int n = 0; n < NSTATE; ++n)
    A2[n] = -__expf(A_log[d * NSTATE + n]) * 1.4426950408889634f;  // A * log2(e)

  float h[NSTATE];
#pragma unroll
  for (int n = 0; n < NSTATE; ++n) h[n] = 0.f;

  const float Dv = Dp[d];

  for (int t = 0; t < NL; ++t) {
    const size_t row = (size_t)(b * NL + t);
    const size_t rd = row * D_INNER + d;
    const float dtv = dt[rd];
    const float xv = xc[rd];
    const float* pr = proj + row * (DT_RANK + 2 * NSTATE);
    const float dx = dtv * xv;
    float accv = 0.f;
#pragma unroll
    for (int n = 0; n < NSTATE; ++n) {
      const float dec = exp2f(dtv * A2[n]);
      h[n] = fmaf(h[n], dec, dx * pr[DT_RANK + n]);
      accv = fmaf(h[n], pr[DT_RANK + NSTATE + n], accv);
    }
    const float zv = xz[row * (2 * D_INNER) + D_INNER + d];
    float yv = fmaf(xv, Dv, accv);
    yv *= zv / (1.f + __expf(-zv));
    xc[rd] = yv;
  }
}

// ---------------------------------------------------------------------------
// out = LayerNorm(x + res) * w + b.  One wave per row (D_MODEL=512 -> 8/lane).
// ---------------------------------------------------------------------------
__global__ __launch_bounds__(256) void add_ln(
    const float* __restrict__ x,
    const float* __restrict__ res,
    const float* __restrict__ w,
    const float* __restrict__ bln,
    float* __restrict__ out)
{
  const int wave = threadIdx.x >> 6;
  const int lane = threadIdx.x & 63;
  const int row = blockIdx.x * 4 + wave;
  const float* xr = x + (size_t)row * D_MODEL;
  const float* rr = res + (size_t)row * D_MODEL;

  float v[8];
  float s = 0.f, s2 = 0.f;
#pragma unroll
  for (int i = 0; i < 8; ++i) {
    const float t = xr[lane + i * 64] + rr[lane + i * 64];
    v[i] = t; s += t; s2 = fmaf(t, t, s2);
  }
#pragma unroll
  for (int off = 32; off; off >>= 1) {
    s += __shfl_xor(s, off);
    s2 += __shfl_xor(s2, off);
  }
  const float mean = s * (1.f / D_MODEL);
  const float var = s2 * (1.f / D_MODEL) - mean * mean;
  const float rstd = rsqrtf(var + 1e-5f);
#pragma unroll
  for (int i = 0; i < 8; ++i) {
    const int c = lane + i * 64;
    out[(size_t)row * D_MODEL + c] = (v[i] - mean) * rstd * w[c] + bln[c];
  }
}

// Final: out[b, :] = h[b, NL-1, :]
__global__ __launch_bounds__(256) void extract_last(
    const float* __restrict__ h, float* __restrict__ out)
{
  const int idx = blockIdx.x * 256 + threadIdx.x;
  if (idx < NB * D_MODEL) {
    const int b = idx >> 9, j = idx & (D_MODEL - 1);
    out[idx] = h[((size_t)(b * NL + NL - 1)) * D_MODEL + j];
  }
}

// ---------------------------------------------------------------------------
extern "C" void kernel_launch(void* const* d_in, const int* in_sizes, int n_in,
                              void* d_out, int out_size, void* d_ws, size_t ws_size,
                              hipStream_t stream)
{
  const float* x         = (const float*)d_in[0];
  const float* input_w   = (const float*)d_in[1];
  const float* input_b   = (const float*)d_in[2];
  const float* in_proj_w = (const float*)d_in[3];
  const float* in_proj_b = (const float*)d_in[4];
  const float* conv_w    = (const float*)d_in[5];
  const float* conv_b    = (const float*)d_in[6];
  const float* x_proj_w  = (const float*)d_in[7];
  const float* dt_proj_w = (const float*)d_in[8];
  const float* dt_proj_b = (const float*)d_in[9];
  const float* A_log     = (const float*)d_in[10];
  const float* Dp        = (const float*)d_in[11];
  const float* out_proj_w= (const float*)d_in[12];
  const float* out_proj_b= (const float*)d_in[13];
  const float* ln_w      = (const float*)d_in[14];
  const float* ln_b      = (const float*)d_in[15];

  float* ws = (float*)d_ws;
  float* h0   = ws;                               // 4096*512
  float* h1   = h0 + (size_t)NROWS * D_MODEL;     // 4096*512
  float* xz   = h1 + (size_t)NROWS * D_MODEL;     // 4096*2048
  float* xc   = xz + (size_t)NROWS * 2 * D_INNER; // 4096*1024
  float* proj = xc + (size_t)NROWS * D_INNER;     // 4096*64
  float* dtb  = proj + (size_t)NROWS * (DT_RANK + 2 * NSTATE); // 4096*1024
  float* tmp  = xz;  // out_proj result aliases xz (xz dead after scan)

  // h0 = x @ input_w^T + input_b   (M=4096, N=512, K=64)
  gemm_atb<<<dim3(D_MODEL / 64, NROWS / 64), 256, 0, stream>>>(
      x, IN_DIM, input_w, input_b, h0, NROWS, D_MODEL, IN_DIM, 0);

  float* hc = h0;
  float* hn = h1;

  for (int l = 0; l < N_LAYERS; ++l) {
    const float* iw = in_proj_w + (size_t)l * 2 * D_INNER * D_MODEL;
    const float* ib = in_proj_b + (size_t)l * 2 * D_INNER;
    const float* cw = conv_w    + (size_t)l * D_INNER * KCONV;
    const float* cb = conv_b    + (size_t)l * D_INNER;
    const float* xw = x_proj_w  + (size_t)l * (DT_RANK + 2 * NSTATE) * D_INNER;
    const float* dw = dt_proj_w + (size_t)l * D_INNER * DT_RANK;
    const float* db = dt_proj_b + (size_t)l * D_INNER;
    const float* Al = A_log     + (size_t)l * D_INNER * NSTATE;
    const float* Dl = Dp        + (size_t)l * D_INNER;
    const float* ow = out_proj_w+ (size_t)l * D_MODEL * D_INNER;
    const float* ob = out_proj_b+ (size_t)l * D_MODEL;
    const float* lw = ln_w      + (size_t)l * D_MODEL;
    const float* lb = ln_b      + (size_t)l * D_MODEL;

    // xz = hc @ iw^T + ib   (M=4096, N=2048, K=512)
    gemm_atb<<<dim3(2 * D_INNER / 64, NROWS / 64), 256, 0, stream>>>(
        hc, D_MODEL, iw, ib, xz, NROWS, 2 * D_INNER, D_MODEL, 0);

    // xc = silu(causal depthwise conv(xp) + cb)
    conv_silu<<<NROWS * D_INNER / 256, 256, 0, stream>>>(xz, cw, cb, xc);

    // proj = xc @ xw^T      (M=4096, N=64, K=1024)
    gemm_atb<<<dim3(1, NROWS / 64), 256, 0, stream>>>(
        xc, D_INNER, xw, nullptr, proj, NROWS, DT_RANK + 2 * NSTATE, D_INNER, 0);

    // dt = softplus(dtl @ dw^T + db)  (A = proj[:, :32], lda=64; M=4096,N=1024,K=32)
    gemm_atb<<<dim3(D_INNER / 64, NROWS / 64), 256, 0, stream>>>(
        proj, DT_RANK + 2 * NSTATE, dw, db, dtb, NROWS, D_INNER, DT_RANK, 1);

    // selective scan + D skip + gate: xc <- gated y
    scan_kernel<<<dim3(D_INNER / 256, NB), 256, 0, stream>>>(
        dtb, proj, xz, Al, Dl, xc);

    // tmp = y @ ow^T + ob   (M=4096, N=512, K=1024)
    gemm_atb<<<dim3(D_MODEL / 64, NROWS / 64), 256, 0, stream>>>(
        xc, D_INNER, ow, ob, tmp, NROWS, D_MODEL, D_INNER, 0);

    // hn = LN(tmp + hc)
    add_ln<<<NROWS / 4, 256, 0, stream>>>(tmp, hc, lw, lb, hn);

    float* t2 = hc; hc = hn; hn = t2;
  }

  extract_last<<<(NB * D_MODEL + 255) / 256, 256, 0, stream>>>(hc, (float*)d_out);
}

// Round 2
// 1460.446 us; speedup vs baseline: 2.1571x; 2.1571x over previous
//
#include <hip/hip_runtime.h>
#include <hip/hip_bf16.h>
#include <cstddef>

// Problem constants
#define NB 4
#define NL 1024
#define IN_DIM 64
#define D_MODEL 512
#define N_LAYERS 3
#define D_INNER 1024
#define NSTATE 16
#define DT_RANK 32
#define KCONV 4
#define NROWS (NB * NL)   // 4096
#define CHUNK 16
#define NCHUNK (NL / CHUNK)  // 64
#define LOG2E 1.4426950408889634f

// ---------------------------------------------------------------------------
// Generic tiled fp32 GEMM: C[M,N] = A[M,lda(>=K)] @ W[N,K]^T (+bias) (+act)
// act: 0 = none, 1 = softplus
// Requires: M % 64 == 0, N % 64 == 0, K % 16 == 0.
// ---------------------------------------------------------------------------
__global__ __launch_bounds__(256) void gemm_atb(
    const float* __restrict__ A, int lda,
    const float* __restrict__ W,
    const float* __restrict__ bias,
    float* __restrict__ C,
    int M, int N, int K, int act)
{
  __shared__ float sa[16][65];
  __shared__ float sb[16][65];
  const int tid = threadIdx.x;
  const int tx = tid & 15, ty = tid >> 4;
  const int m0 = blockIdx.y * 64, n0 = blockIdx.x * 64;
  const int lrow = tid >> 2;        // 0..63
  const int lk = (tid & 3) << 2;    // 0,4,8,12
  float acc[4][4] = {};

  for (int k0 = 0; k0 < K; k0 += 16) {
    float4 av = *(const float4*)(A + (size_t)(m0 + lrow) * lda + k0 + lk);
    float4 wv = *(const float4*)(W + (size_t)(n0 + lrow) * K + k0 + lk);
    sa[lk + 0][lrow] = av.x; sa[lk + 1][lrow] = av.y;
    sa[lk + 2][lrow] = av.z; sa[lk + 3][lrow] = av.w;
    sb[lk + 0][lrow] = wv.x; sb[lk + 1][lrow] = wv.y;
    sb[lk + 2][lrow] = wv.z; sb[lk + 3][lrow] = wv.w;
    __syncthreads();
#pragma unroll
    for (int kk = 0; kk < 16; ++kk) {
      float a[4], b[4];
#pragma unroll
      for (int i = 0; i < 4; ++i) a[i] = sa[kk][(ty << 2) + i];
#pragma unroll
      for (int j = 0; j < 4; ++j) b[j] = sb[kk][(tx << 2) + j];
#pragma unroll
      for (int i = 0; i < 4; ++i)
#pragma unroll
        for (int j = 0; j < 4; ++j)
          acc[i][j] = fmaf(a[i], b[j], acc[i][j]);
    }
    __syncthreads();
  }

#pragma unroll
  for (int i = 0; i < 4; ++i) {
    const int m = m0 + (ty << 2) + i;
#pragma unroll
    for (int j = 0; j < 4; ++j) {
      const int n = n0 + (tx << 2) + j;
      float v = acc[i][j];
      if (bias) v += bias[n];
      if (act == 1) v = (v > 20.f) ? v : log1pf(__expf(v));
      C[(size_t)m * N + n] = v;
    }
  }
}

// ---------------------------------------------------------------------------
// Depthwise causal conv (K=4) + SiLU.
// ---------------------------------------------------------------------------
__global__ __launch_bounds__(256) void conv_silu(
    const float* __restrict__ xz,
    const float* __restrict__ cw,
    const float* __restrict__ cb,
    float* __restrict__ xc)
{
  const int idx = blockIdx.x * 256 + threadIdx.x;   // over NB*NL*D_INNER
  const int d = idx & (D_INNER - 1);
  const int bt = idx >> 10;
  const int t = bt & (NL - 1);
  const int b = bt >> 10;

  float accv = cb[d];
#pragma unroll
  for (int j = 0; j < KCONV; ++j) {
    const int tt = t - (KCONV - 1) + j;
    if (tt >= 0)
      accv = fmaf(xz[((size_t)(b * NL + tt)) * (2 * D_INNER) + d], cw[d * KCONV + j], accv);
  }
  const float sig = 1.f / (1.f + __expf(-accv));
  xc[idx] = accv * sig;
}

// ---------------------------------------------------------------------------
// Chunked selective scan.
// S_loc layout: S[((b*NCHUNK + c)*NSTATE + n)*D_INNER + d]
// sumdt layout: [ (b*NCHUNK + c)*D_INNER + d ]
// ---------------------------------------------------------------------------

// Phase A: per (b, chunk, d) local scan from h=0; store final state + dt-sum.
__global__ __launch_bounds__(256) void scan_phase1(
    const float* __restrict__ dt,
    const float* __restrict__ proj,
    const float* __restrict__ xc,
    const float* __restrict__ A_log,
    float* __restrict__ S_loc,
    float* __restrict__ sumdt)
{
  const int d = blockIdx.x * 256 + threadIdx.x;  // 0..1023
  const int c = blockIdx.y;                      // chunk
  const int b = blockIdx.z;

  float A2[NSTATE];
#pragma unroll
  for (int n = 0; n < NSTATE; ++n)
    A2[n] = -__expf(A_log[d * NSTATE + n]) * LOG2E;

  float h[NSTATE];
#pragma unroll
  for (int n = 0; n < NSTATE; ++n) h[n] = 0.f;
  float sdt = 0.f;

  const int t0 = c * CHUNK;
#pragma unroll 4
  for (int tt = 0; tt < CHUNK; ++tt) {
    const size_t row = (size_t)(b * NL + t0 + tt);
    const float dtv = dt[row * D_INNER + d];
    const float xv = xc[row * D_INNER + d];
    const float* pr = proj + row * (DT_RANK + 2 * NSTATE);
    sdt += dtv;
    const float dx = dtv * xv;
#pragma unroll
    for (int n = 0; n < NSTATE; ++n)
      h[n] = fmaf(h[n], exp2f(dtv * A2[n]), dx * pr[DT_RANK + n]);
  }

  const size_t cbase = (size_t)(b * NCHUNK + c);
  sumdt[cbase * D_INNER + d] = sdt;
#pragma unroll
  for (int n = 0; n < NSTATE; ++n)
    S_loc[(cbase * NSTATE + n) * D_INNER + d] = h[n];
}

// Phase B: carry scan across chunks, per (b, n, d). Writes H_in (same layout
// as S_loc): the state at the START of each chunk.
__global__ __launch_bounds__(256) void scan_carry(
    const float* __restrict__ S_loc,
    const float* __restrict__ sumdt,
    const float* __restrict__ A_log,
    float* __restrict__ H_in)
{
  const int idx = blockIdx.x * 256 + threadIdx.x;  // over NB*NSTATE*D_INNER
  const int d = idx & (D_INNER - 1);
  const int n = (idx >> 10) & (NSTATE - 1);
  const int b = idx >> 14;

  const float A2n = -__expf(A_log[d * NSTATE + n]) * LOG2E;

  float H = 0.f;
  for (int c = 0; c < NCHUNK; ++c) {
    const size_t cbase = (size_t)(b * NCHUNK + c);
    H_in[(cbase * NSTATE + n) * D_INNER + d] = H;
    const float sdt = sumdt[cbase * D_INNER + d];
    H = fmaf(H, exp2f(A2n * sdt), S_loc[(cbase * NSTATE + n) * D_INNER + d]);
  }
}

// Phase C: per (b, chunk, d) local scan seeded with H_in; emit gated y.
__global__ __launch_bounds__(256) void scan_phase2(
    const float* __restrict__ dt,
    const float* __restrict__ proj,
    const float* __restrict__ xz,     // for z = xz[..., D_INNER:]
    const float* __restrict__ A_log,
    const float* __restrict__ Dp,
    const float* __restrict__ H_in,
    float* xc)                        // in: xc, out: gated y (same buffer)
{
  const int d = blockIdx.x * 256 + threadIdx.x;
  const int c = blockIdx.y;
  const int b = blockIdx.z;

  float A2[NSTATE];
#pragma unroll
  for (int n = 0; n < NSTATE; ++n)
    A2[n] = -__expf(A_log[d * NSTATE + n]) * LOG2E;

  const size_t cbase = (size_t)(b * NCHUNK + c);
  float h[NSTATE];
#pragma unroll
  for (int n = 0; n < NSTATE; ++n)
    h[n] = H_in[(cbase * NSTATE + n) * D_INNER + d];

  const float Dv = Dp[d];
  const int t0 = c * CHUNK;

#pragma unroll 4
  for (int tt = 0; tt < CHUNK; ++tt) {
    const size_t row = (size_t)(b * NL + t0 + tt);
    const size_t rd = row * D_INNER + d;
    const float dtv = dt[rd];
    const float xv = xc[rd];
    const float* pr = proj + row * (DT_RANK + 2 * NSTATE);
    const float dx = dtv * xv;
    float accv = 0.f;
#pragma unroll
    for (int n = 0; n < NSTATE; ++n) {
      h[n] = fmaf(h[n], exp2f(dtv * A2[n]), dx * pr[DT_RANK + n]);
      accv = fmaf(h[n], pr[DT_RANK + NSTATE + n], accv);
    }
    const float zv = xz[row * (2 * D_INNER) + D_INNER + d];
    float yv = fmaf(xv, Dv, accv);
    yv *= zv / (1.f + __expf(-zv));
    xc[rd] = yv;
  }
}

// ---------------------------------------------------------------------------
// out = LayerNorm(x + res) * w + b.  One wave per row.
// ---------------------------------------------------------------------------
__global__ __launch_bounds__(256) void add_ln(
    const float* __restrict__ x,
    const float* __restrict__ res,
    const float* __restrict__ w,
    const float* __restrict__ bln,
    float* __restrict__ out)
{
  const int wave = threadIdx.x >> 6;
  const int lane = threadIdx.x & 63;
  const int row = blockIdx.x * 4 + wave;
  const float* xr = x + (size_t)row * D_MODEL;
  const float* rr = res + (size_t)row * D_MODEL;

  float v[8];
  float s = 0.f, s2 = 0.f;
#pragma unroll
  for (int i = 0; i < 8; ++i) {
    const float t = xr[lane + i * 64] + rr[lane + i * 64];
    v[i] = t; s += t; s2 = fmaf(t, t, s2);
  }
#pragma unroll
  for (int off = 32; off; off >>= 1) {
    s += __shfl_xor(s, off);
    s2 += __shfl_xor(s2, off);
  }
  const float mean = s * (1.f / D_MODEL);
  const float var = s2 * (1.f / D_MODEL) - mean * mean;
  const float rstd = rsqrtf(var + 1e-5f);
#pragma unroll
  for (int i = 0; i < 8; ++i) {
    const int c = lane + i * 64;
    out[(size_t)row * D_MODEL + c] = (v[i] - mean) * rstd * w[c] + bln[c];
  }
}

// Final: out[b, :] = h[b, NL-1, :]
__global__ __launch_bounds__(256) void extract_last(
    const float* __restrict__ h, float* __restrict__ out)
{
  const int idx = blockIdx.x * 256 + threadIdx.x;
  if (idx < NB * D_MODEL) {
    const int b = idx >> 9, j = idx & (D_MODEL - 1);
    out[idx] = h[((size_t)(b * NL + NL - 1)) * D_MODEL + j];
  }
}

// ---------------------------------------------------------------------------
extern "C" void kernel_launch(void* const* d_in, const int* in_sizes, int n_in,
                              void* d_out, int out_size, void* d_ws, size_t ws_size,
                              hipStream_t stream)
{
  const float* x         = (const float*)d_in[0];
  const float* input_w   = (const float*)d_in[1];
  const float* input_b   = (const float*)d_in[2];
  const float* in_proj_w = (const float*)d_in[3];
  const float* in_proj_b = (const float*)d_in[4];
  const float* conv_w    = (const float*)d_in[5];
  const float* conv_b    = (const float*)d_in[6];
  const float* x_proj_w  = (const float*)d_in[7];
  const float* dt_proj_w = (const float*)d_in[8];
  const float* dt_proj_b = (const float*)d_in[9];
  const float* A_log     = (const float*)d_in[10];
  const float* Dp        = (const float*)d_in[11];
  const float* out_proj_w= (const float*)d_in[12];
  const float* out_proj_b= (const float*)d_in[13];
  const float* ln_w      = (const float*)d_in[14];
  const float* ln_b      = (const float*)d_in[15];

  float* ws = (float*)d_ws;
  float* h0   = ws;                               // 4096*512
  float* h1   = h0 + (size_t)NROWS * D_MODEL;     // 4096*512
  float* xz   = h1 + (size_t)NROWS * D_MODEL;     // 4096*2048
  float* xc   = xz + (size_t)NROWS * 2 * D_INNER; // 4096*1024
  float* proj = xc + (size_t)NROWS * D_INNER;     // 4096*64
  float* dtb  = proj + (size_t)NROWS * (DT_RANK + 2 * NSTATE); // 4096*1024
  float* Sloc = dtb + (size_t)NROWS * D_INNER;    // 4*64*16*1024 = 4M floats
  float* Hin  = Sloc + (size_t)NB * NCHUNK * NSTATE * D_INNER; // 4M floats
  float* sdt  = Hin + (size_t)NB * NCHUNK * NSTATE * D_INNER;  // 4*64*1024
  float* tmp  = xz;  // out_proj result aliases xz (xz dead after scan)

  // h0 = x @ input_w^T + input_b   (M=4096, N=512, K=64)
  gemm_atb<<<dim3(D_MODEL / 64, NROWS / 64), 256, 0, stream>>>(
      x, IN_DIM, input_w, input_b, h0, NROWS, D_MODEL, IN_DIM, 0);

  float* hc = h0;
  float* hn = h1;

  for (int l = 0; l < N_LAYERS; ++l) {
    const float* iw = in_proj_w + (size_t)l * 2 * D_INNER * D_MODEL;
    const float* ib = in_proj_b + (size_t)l * 2 * D_INNER;
    const float* cw = conv_w    + (size_t)l * D_INNER * KCONV;
    const float* cb = conv_b    + (size_t)l * D_INNER;
    const float* xw = x_proj_w  + (size_t)l * (DT_RANK + 2 * NSTATE) * D_INNER;
    const float* dw = dt_proj_w + (size_t)l * D_INNER * DT_RANK;
    const float* db = dt_proj_b + (size_t)l * D_INNER;
    const float* Al = A_log     + (size_t)l * D_INNER * NSTATE;
    const float* Dl = Dp        + (size_t)l * D_INNER;
    const float* ow = out_proj_w+ (size_t)l * D_MODEL * D_INNER;
    const float* ob = out_proj_b+ (size_t)l * D_MODEL;
    const float* lw = ln_w      + (size_t)l * D_MODEL;
    const float* lb = ln_b      + (size_t)l * D_MODEL;

    // xz = hc @ iw^T + ib   (M=4096, N=2048, K=512)
    gemm_atb<<<dim3(2 * D_INNER / 64, NROWS / 64), 256, 0, stream>>>(
        hc, D_MODEL, iw, ib, xz, NROWS, 2 * D_INNER, D_MODEL, 0);

    // xc = silu(causal depthwise conv(xp) + cb)
    conv_silu<<<NROWS * D_INNER / 256, 256, 0, stream>>>(xz, cw, cb, xc);

    // proj = xc @ xw^T      (M=4096, N=64, K=1024)
    gemm_atb<<<dim3(1, NROWS / 64), 256, 0, stream>>>(
        xc, D_INNER, xw, nullptr, proj, NROWS, DT_RANK + 2 * NSTATE, D_INNER, 0);

    // dt = softplus(dtl @ dw^T + db)  (A = proj[:, :32], lda=64)
    gemm_atb<<<dim3(D_INNER / 64, NROWS / 64), 256, 0, stream>>>(
        proj, DT_RANK + 2 * NSTATE, dw, db, dtb, NROWS, D_INNER, DT_RANK, 1);

    // Chunked selective scan
    scan_phase1<<<dim3(D_INNER / 256, NCHUNK, NB), 256, 0, stream>>>(
        dtb, proj, xc, Al, Sloc, sdt);
    scan_carry<<<(NB * NSTATE * D_INNER) / 256, 256, 0, stream>>>(
        Sloc, sdt, Al, Hin);
    scan_phase2<<<dim3(D_INNER / 256, NCHUNK, NB), 256, 0, stream>>>(
        dtb, proj, xz, Al, Dl, Hin, xc);

    // tmp = y @ ow^T + ob   (M=4096, N=512, K=1024)
    gemm_atb<<<dim3(D_MODEL / 64, NROWS / 64), 256, 0, stream>>>(
        xc, D_INNER, ow, ob, tmp, NROWS, D_MODEL, D_INNER, 0);

    // hn = LN(tmp + hc)
    add_ln<<<NROWS / 4, 256, 0, stream>>>(tmp, hc, lw, lb, hn);

    float* t2 = hc; hc = hn; hn = t2;
  }

  extract_last<<<(NB * D_MODEL + 255) / 256, 256, 0, stream>>>(hc, (float*)d_out);
}

// Round 4
// 578.032 us; speedup vs baseline: 5.4500x; 2.5266x over previous
//
#include <hip/hip_runtime.h>
#include <hip/hip_bf16.h>
#include <cstddef>
#include <cstdint>

// Problem constants
#define NB 4
#define NL 1024
#define IN_DIM 64
#define D_MODEL 512
#define N_LAYERS 3
#define D_INNER 1024
#define NSTATE 16
#define DT_RANK 32
#define KCONV 4
#define NROWS (NB * NL)   // 4096
#define CHUNK 16
#define NCHUNK (NL / CHUNK)  // 64
#define LOG2E 1.4426950408889634f

typedef __attribute__((ext_vector_type(8))) short short8;
typedef __attribute__((ext_vector_type(4))) float f32x4;
typedef __attribute__((ext_vector_type(4))) unsigned short us4;
typedef unsigned short ushort_t;

// float -> bf16 round-to-nearest-even
__device__ __forceinline__ ushort_t f2b1(float x) {
  uint32_t u = __builtin_bit_cast(uint32_t, x);
  u += 0x7fffu + ((u >> 16) & 1u);
  return (ushort_t)(u >> 16);
}

// ---------------------------------------------------------------------------
// Convert fp32 tensor -> bf16 (as ushort). n must be a multiple of 4.
// ---------------------------------------------------------------------------
__global__ __launch_bounds__(256) void f2b_kernel(
    const float* __restrict__ in, ushort_t* __restrict__ out, int n)
{
  const int i = (blockIdx.x * 256 + threadIdx.x) * 4;
  if (i >= n) return;
  const float4 v = *(const float4*)(in + i);
  us4 o;
  o.x = f2b1(v.x); o.y = f2b1(v.y); o.z = f2b1(v.z); o.w = f2b1(v.w);
  *(us4*)(out + i) = o;
}

// ---------------------------------------------------------------------------
// bf16 MFMA GEMM: C[M,N] = A[M,lda] @ W[N,K]^T (+bias) (+act)
// A, W are bf16 (ushort). Accumulate fp32. Writes fp32 Cf and/or bf16 Cb.
// 256 threads = 4 waves in 2x2; wave computes (MF*16) x (NF*16).
// Requires BM = MF*32, BN = NF*32, M%BM==0, N%BN==0, K%32==0, BM,BN >= 64.
// ---------------------------------------------------------------------------
template<int BM, int BN, int MF, int NF, int ACT, bool WF32, bool WB16>
__global__ __launch_bounds__(256) void gemm_mfma(
    const ushort_t* __restrict__ A, int lda,
    const ushort_t* __restrict__ W,
    const float* __restrict__ bias,
    float* __restrict__ Cf, ushort_t* __restrict__ Cb,
    int M, int N, int K)
{
  constexpr int LDSK = 48;            // 32 + 16 pad shorts: rows 96B (16B-aligned)
  constexpr int CA = BM / 64;         // 16B chunks per thread for A tile
  constexpr int CB = BN / 64;
  __shared__ __align__(16) short sa[BM * LDSK];
  __shared__ __align__(16) short sb[BN * LDSK];

  const int tid = threadIdx.x;
  const int l = tid & 63;
  const int wid = tid >> 6;
  const int wrow = (wid >> 1) * (BM / 2);
  const int wcol = (wid & 1) * (BN / 2);
  const int m0 = blockIdx.y * BM;
  const int n0 = blockIdx.x * BN;

  f32x4 acc[MF][NF] = {};
  short8 ra[CA], rb[CB];

  auto loadg = [&](int k0) {
#pragma unroll
    for (int c = 0; c < CA; ++c) {
      const int chunk = c * 256 + tid;          // < BM*4
      const int row = chunk >> 2, colb = chunk & 3;
      ra[c] = *(const short8*)(A + (size_t)(m0 + row) * lda + k0 + colb * 8);
    }
#pragma unroll
    for (int c = 0; c < CB; ++c) {
      const int chunk = c * 256 + tid;
      const int row = chunk >> 2, colb = chunk & 3;
      rb[c] = *(const short8*)(W + (size_t)(n0 + row) * K + k0 + colb * 8);
    }
  };
  auto store_lds = [&]() {
#pragma unroll
    for (int c = 0; c < CA; ++c) {
      const int chunk = c * 256 + tid;
      *(short8*)(sa + (chunk >> 2) * LDSK + (chunk & 3) * 8) = ra[c];
    }
#pragma unroll
    for (int c = 0; c < CB; ++c) {
      const int chunk = c * 256 + tid;
      *(short8*)(sb + (chunk >> 2) * LDSK + (chunk & 3) * 8) = rb[c];
    }
  };

  loadg(0);
  for (int k0 = 0; k0 < K; k0 += 32) {
    __syncthreads();                 // previous tile's reads complete
    store_lds();
    __syncthreads();                 // tile ready
    if (k0 + 32 < K) loadg(k0 + 32); // prefetch next tile (overlaps compute)

    short8 af[MF], bfr[NF];
#pragma unroll
    for (int mi = 0; mi < MF; ++mi)
      af[mi] = *(const short8*)(sa + (wrow + mi * 16 + (l & 15)) * LDSK + (l >> 4) * 8);
#pragma unroll
    for (int nj = 0; nj < NF; ++nj)
      bfr[nj] = *(const short8*)(sb + (wcol + nj * 16 + (l & 15)) * LDSK + (l >> 4) * 8);
#pragma unroll
    for (int mi = 0; mi < MF; ++mi)
#pragma unroll
      for (int nj = 0; nj < NF; ++nj)
        acc[mi][nj] = __builtin_amdgcn_mfma_f32_16x16x32_bf16(
            af[mi], bfr[nj], acc[mi][nj], 0, 0, 0);
  }

  // Epilogue: C/D layout col=lane&15, row=(lane>>4)*4+reg
#pragma unroll
  for (int nj = 0; nj < NF; ++nj) {
    const int col = n0 + wcol + nj * 16 + (l & 15);
    const float bv = bias ? bias[col] : 0.f;
#pragma unroll
    for (int mi = 0; mi < MF; ++mi) {
#pragma unroll
      for (int q = 0; q < 4; ++q) {
        const int row = m0 + wrow + mi * 16 + (l >> 4) * 4 + q;
        float v = acc[mi][nj][q] + bv;
        if (ACT == 1) v = (v > 20.f) ? v : log1pf(__expf(v));
        if (WF32) Cf[(size_t)row * N + col] = v;
        if (WB16) Cb[(size_t)row * N + col] = f2b1(v);
      }
    }
  }
}

// ---------------------------------------------------------------------------
// Depthwise causal conv (K=4) + SiLU. Dual write fp32 + bf16.
// ---------------------------------------------------------------------------
__global__ __launch_bounds__(256) void conv_silu(
    const float* __restrict__ xz,
    const float* __restrict__ cw,
    const float* __restrict__ cb,
    float* __restrict__ xc,
    ushort_t* __restrict__ xcb)
{
  const int idx = blockIdx.x * 256 + threadIdx.x;   // over NB*NL*D_INNER
  const int d = idx & (D_INNER - 1);
  const int bt = idx >> 10;
  const int t = bt & (NL - 1);
  const int b = bt >> 10;

  float accv = cb[d];
#pragma unroll
  for (int j = 0; j < KCONV; ++j) {
    const int tt = t - (KCONV - 1) + j;
    if (tt >= 0)
      accv = fmaf(xz[((size_t)(b * NL + tt)) * (2 * D_INNER) + d], cw[d * KCONV + j], accv);
  }
  const float sig = 1.f / (1.f + __expf(-accv));
  const float val = accv * sig;
  xc[idx] = val;
  xcb[idx] = f2b1(val);
}

// ---------------------------------------------------------------------------
// Chunked selective scan (fp32 throughout).
// ---------------------------------------------------------------------------
__global__ __launch_bounds__(256) void scan_phase1(
    const float* __restrict__ dt,
    const float* __restrict__ proj,
    const float* __restrict__ xc,
    const float* __restrict__ A_log,
    float* __restrict__ S_loc,
    float* __restrict__ sumdt)
{
  const int d = blockIdx.x * 256 + threadIdx.x;
  const int c = blockIdx.y;
  const int b = blockIdx.z;

  float A2[NSTATE];
#pragma unroll
  for (int n = 0; n < NSTATE; ++n)
    A2[n] = -__expf(A_log[d * NSTATE + n]) * LOG2E;

  float h[NSTATE];
#pragma unroll
  for (int n = 0; n < NSTATE; ++n) h[n] = 0.f;
  float sdt = 0.f;

  const int t0 = c * CHUNK;
#pragma unroll 4
  for (int tt = 0; tt < CHUNK; ++tt) {
    const size_t row = (size_t)(b * NL + t0 + tt);
    const float dtv = dt[row * D_INNER + d];
    const float xv = xc[row * D_INNER + d];
    const float* pr = proj + row * (DT_RANK + 2 * NSTATE);
    sdt += dtv;
    const float dx = dtv * xv;
#pragma unroll
    for (int n = 0; n < NSTATE; ++n)
      h[n] = fmaf(h[n], exp2f(dtv * A2[n]), dx * pr[DT_RANK + n]);
  }

  const size_t cbase = (size_t)(b * NCHUNK + c);
  sumdt[cbase * D_INNER + d] = sdt;
#pragma unroll
  for (int n = 0; n < NSTATE; ++n)
    S_loc[(cbase * NSTATE + n) * D_INNER + d] = h[n];
}

__global__ __launch_bounds__(256) void scan_carry(
    const float* __restrict__ S_loc,
    const float* __restrict__ sumdt,
    const float* __restrict__ A_log,
    float* __restrict__ H_in)
{
  const int idx = blockIdx.x * 256 + threadIdx.x;
  const int d = idx & (D_INNER - 1);
  const int n = (idx >> 10) & (NSTATE - 1);
  const int b = idx >> 14;

  const float A2n = -__expf(A_log[d * NSTATE + n]) * LOG2E;

  float H = 0.f;
  for (int c = 0; c < NCHUNK; ++c) {
    const size_t cbase = (size_t)(b * NCHUNK + c);
    H_in[(cbase * NSTATE + n) * D_INNER + d] = H;
    const float sdt = sumdt[cbase * D_INNER + d];
    H = fmaf(H, exp2f(A2n * sdt), S_loc[(cbase * NSTATE + n) * D_INNER + d]);
  }
}

__global__ __launch_bounds__(256) void scan_phase2(
    const float* __restrict__ dt,
    const float* __restrict__ proj,
    const float* __restrict__ xz,     // z = xz[..., D_INNER:]
    const float* __restrict__ A_log,
    const float* __restrict__ Dp,
    const float* __restrict__ H_in,
    const float* __restrict__ xc,
    ushort_t* __restrict__ yb)        // gated y, bf16 (feeds out_proj)
{
  const int d = blockIdx.x * 256 + threadIdx.x;
  const int c = blockIdx.y;
  const int b = blockIdx.z;

  float A2[NSTATE];
#pragma unroll
  for (int n = 0; n < NSTATE; ++n)
    A2[n] = -__expf(A_log[d * NSTATE + n]) * LOG2E;

  const size_t cbase = (size_t)(b * NCHUNK + c);
  float h[NSTATE];
#pragma unroll
  for (int n = 0; n < NSTATE; ++n)
    h[n] = H_in[(cbase * NSTATE + n) * D_INNER + d];

  const float Dv = Dp[d];
  const int t0 = c * CHUNK;

#pragma unroll 4
  for (int tt = 0; tt < CHUNK; ++tt) {
    const size_t row = (size_t)(b * NL + t0 + tt);
    const size_t rd = row * D_INNER + d;
    const float dtv = dt[rd];
    const float xv = xc[rd];
    const float* pr = proj + row * (DT_RANK + 2 * NSTATE);
    const float dx = dtv * xv;
    float accv = 0.f;
#pragma unroll
    for (int n = 0; n < NSTATE; ++n) {
      h[n] = fmaf(h[n], exp2f(dtv * A2[n]), dx * pr[DT_RANK + n]);
      accv = fmaf(h[n], pr[DT_RANK + NSTATE + n], accv);
    }
    const float zv = xz[row * (2 * D_INNER) + D_INNER + d];
    float yv = fmaf(xv, Dv, accv);
    yv *= zv / (1.f + __expf(-zv));
    yb[rd] = f2b1(yv);
  }
}

// ---------------------------------------------------------------------------
// out = LayerNorm(x + res) * w + b.  One wave per row. Dual write fp32 + bf16.
// ---------------------------------------------------------------------------
__global__ __launch_bounds__(256) void add_ln(
    const float* __restrict__ x,
    const float* __restrict__ res,
    const float* __restrict__ w,
    const float* __restrict__ bln,
    float* __restrict__ out,
    ushort_t* __restrict__ outb)
{
  const int wave = threadIdx.x >> 6;
  const int lane = threadIdx.x & 63;
  const int row = blockIdx.x * 4 + wave;
  const float* xr = x + (size_t)row * D_MODEL;
  const float* rr = res + (size_t)row * D_MODEL;

  float v[8];
  float s = 0.f, s2 = 0.f;
#pragma unroll
  for (int i = 0; i < 8; ++i) {
    const float t = xr[lane + i * 64] + rr[lane + i * 64];
    v[i] = t; s += t; s2 = fmaf(t, t, s2);
  }
#pragma unroll
  for (int off = 32; off; off >>= 1) {
    s += __shfl_xor(s, off);
    s2 += __shfl_xor(s2, off);
  }
  const float mean = s * (1.f / D_MODEL);
  const float var = s2 * (1.f / D_MODEL) - mean * mean;
  const float rstd = rsqrtf(var + 1e-5f);
#pragma unroll
  for (int i = 0; i < 8; ++i) {
    const int c = lane + i * 64;
    const float o = (v[i] - mean) * rstd * w[c] + bln[c];
    out[(size_t)row * D_MODEL + c] = o;
    outb[(size_t)row * D_MODEL + c] = f2b1(o);
  }
}

__global__ __launch_bounds__(256) void extract_last(
    const float* __restrict__ h, float* __restrict__ out)
{
  const int idx = blockIdx.x * 256 + threadIdx.x;
  if (idx < NB * D_MODEL) {
    const int b = idx >> 9, j = idx & (D_MODEL - 1);
    out[idx] = h[((size_t)(b * NL + NL - 1)) * D_MODEL + j];
  }
}

// ---------------------------------------------------------------------------
extern "C" void kernel_launch(void* const* d_in, const int* in_sizes, int n_in,
                              void* d_out, int out_size, void* d_ws, size_t ws_size,
                              hipStream_t stream)
{
  const float* x         = (const float*)d_in[0];
  const float* input_w   = (const float*)d_in[1];
  const float* input_b   = (const float*)d_in[2];
  const float* in_proj_w = (const float*)d_in[3];
  const float* in_proj_b = (const float*)d_in[4];
  const float* conv_w    = (const float*)d_in[5];
  const float* conv_b    = (const float*)d_in[6];
  const float* x_proj_w  = (const float*)d_in[7];
  const float* dt_proj_w = (const float*)d_in[8];
  const float* dt_proj_b = (const float*)d_in[9];
  const float* A_log     = (const float*)d_in[10];
  const float* Dp        = (const float*)d_in[11];
  const float* out_proj_w= (const float*)d_in[12];
  const float* out_proj_b= (const float*)d_in[13];
  const float* ln_w      = (const float*)d_in[14];
  const float* ln_b      = (const float*)d_in[15];

  float* p = (float*)d_ws;
  float* h0   = p; p += (size_t)NROWS * D_MODEL;        // 2M
  float* h1   = p; p += (size_t)NROWS * D_MODEL;        // 2M
  float* xz   = p; p += (size_t)NROWS * 2 * D_INNER;    // 8M
  float* xc   = p; p += (size_t)NROWS * D_INNER;        // 4M
  float* proj = p; p += (size_t)NROWS * 64;             // 256K
  float* dtb  = p; p += (size_t)NROWS * D_INNER;        // 4M
  float* Sloc = p; p += (size_t)NB * NCHUNK * NSTATE * D_INNER; // 4M
  float* Hin  = p; p += (size_t)NB * NCHUNK * NSTATE * D_INNER; // 4M
  float* sdt  = p; p += (size_t)NB * NCHUNK * D_INNER;  // 256K
  // bf16 regions (ushort), sizes in floats = elems/2
  ushort_t* hb    = (ushort_t*)p; p += (size_t)NROWS * D_MODEL / 2;
  ushort_t* xb    = (ushort_t*)p; p += (size_t)NROWS * IN_DIM / 2;
  ushort_t* projb = (ushort_t*)p; p += (size_t)NROWS * 64 / 2;
  ushort_t* inwb  = (ushort_t*)p; p += (size_t)D_MODEL * IN_DIM / 2;
  ushort_t* iwb   = (ushort_t*)p; p += (size_t)N_LAYERS * 2 * D_INNER * D_MODEL / 2;
  ushort_t* xwb   = (ushort_t*)p; p += (size_t)N_LAYERS * 64 * D_INNER / 2;
  ushort_t* dwb   = (ushort_t*)p; p += (size_t)N_LAYERS * D_INNER * DT_RANK / 2;
  ushort_t* owb   = (ushort_t*)p; p += (size_t)N_LAYERS * D_MODEL * D_INNER / 2;
  // aliases over dead fp32 buffers
  ushort_t* yb  = (ushort_t*)Sloc;  // written in phase2 (Sloc dead), read by out_proj
  ushort_t* xcb = (ushort_t*)Hin;   // written by conv, read by x_proj (before Hin written)
  float* tmp = xz;                  // out_proj result aliases xz (dead after scan)

  // --- weight/input conversions to bf16 ---
  auto cvt = [&](const float* src, ushort_t* dst, int n) {
    f2b_kernel<<<(n / 4 + 255) / 256, 256, 0, stream>>>(src, dst, n);
  };
  cvt(x, xb, NROWS * IN_DIM);
  cvt(input_w, inwb, D_MODEL * IN_DIM);
  cvt(in_proj_w, iwb, N_LAYERS * 2 * D_INNER * D_MODEL);
  cvt(x_proj_w, xwb, N_LAYERS * 64 * D_INNER);
  cvt(dt_proj_w, dwb, N_LAYERS * D_INNER * DT_RANK);
  cvt(out_proj_w, owb, N_LAYERS * D_MODEL * D_INNER);

  // h0 = x @ input_w^T + input_b   (M=4096, N=512, K=64) -> fp32 + bf16
  gemm_mfma<64, 128, 2, 4, 0, true, true>
      <<<dim3(D_MODEL / 128, NROWS / 64), 256, 0, stream>>>(
      xb, IN_DIM, inwb, input_b, h0, hb, NROWS, D_MODEL, IN_DIM);

  float* hc = h0;
  float* hn = h1;

  for (int l = 0; l < N_LAYERS; ++l) {
    const ushort_t* iw = iwb + (size_t)l * 2 * D_INNER * D_MODEL;
    const float* ib = in_proj_b + (size_t)l * 2 * D_INNER;
    const float* cw = conv_w    + (size_t)l * D_INNER * KCONV;
    const float* cb = conv_b    + (size_t)l * D_INNER;
    const ushort_t* xw = xwb + (size_t)l * 64 * D_INNER;
    const ushort_t* dw = dwb + (size_t)l * D_INNER * DT_RANK;
    const float* db = dt_proj_b + (size_t)l * D_INNER;
    const float* Al = A_log     + (size_t)l * D_INNER * NSTATE;
    const float* Dl = Dp        + (size_t)l * D_INNER;
    const ushort_t* ow = owb + (size_t)l * D_MODEL * D_INNER;
    const float* ob = out_proj_b+ (size_t)l * D_MODEL;
    const float* lw = ln_w      + (size_t)l * D_MODEL;
    const float* lb = ln_b      + (size_t)l * D_MODEL;

    // xz = h @ iw^T + ib   (M=4096, N=2048, K=512) -> fp32
    gemm_mfma<128, 128, 4, 4, 0, true, false>
        <<<dim3(2 * D_INNER / 128, NROWS / 128), 256, 0, stream>>>(
        hb, D_MODEL, iw, ib, xz, nullptr, NROWS, 2 * D_INNER, D_MODEL);

    // xc = silu(conv(xp)) -> fp32 + bf16
    conv_silu<<<NROWS * D_INNER / 256, 256, 0, stream>>>(xz, cw, cb, xc, xcb);

    // proj = xc @ xw^T   (M=4096, N=64, K=1024) -> fp32 + bf16
    gemm_mfma<64, 64, 2, 2, 0, true, true>
        <<<dim3(1, NROWS / 64), 256, 0, stream>>>(
        xcb, D_INNER, xw, nullptr, proj, projb, NROWS, 64, D_INNER);

    // dt = softplus(dtl @ dw^T + db)  (M=4096, N=1024, K=32; A lda=64) -> fp32
    gemm_mfma<128, 128, 4, 4, 1, true, false>
        <<<dim3(D_INNER / 128, NROWS / 128), 256, 0, stream>>>(
        projb, 64, dw, db, dtb, nullptr, NROWS, D_INNER, DT_RANK);

    // Chunked selective scan (fp32); phase2 emits bf16 gated y
    scan_phase1<<<dim3(D_INNER / 256, NCHUNK, NB), 256, 0, stream>>>(
        dtb, proj, xc, Al, Sloc, sdt);
    scan_carry<<<(NB * NSTATE * D_INNER) / 256, 256, 0, stream>>>(
        Sloc, sdt, Al, Hin);
    scan_phase2<<<dim3(D_INNER / 256, NCHUNK, NB), 256, 0, stream>>>(
        dtb, proj, xz, Al, Dl, Hin, xc, yb);

    // tmp = y @ ow^T + ob   (M=4096, N=512, K=1024) -> fp32
    gemm_mfma<64, 128, 2, 4, 0, true, false>
        <<<dim3(D_MODEL / 128, NROWS / 64), 256, 0, stream>>>(
        yb, D_INNER, ow, ob, tmp, nullptr, NROWS, D_MODEL, D_INNER);

    // hn = LN(tmp + hc) -> fp32 + bf16 (hb for next layer's in_proj)
    add_ln<<<NROWS / 4, 256, 0, stream>>>(tmp, hc, lw, lb, hn, hb);

    float* t2 = hc; hc = hn; hn = t2;
  }

  extract_last<<<(NB * D_MODEL + 255) / 256, 256, 0, stream>>>(hc, (float*)d_out);
}